// Round 2
// baseline (422.964 us; speedup 1.0000x reference)
//
#include <hip/hip_runtime.h>
#include <hip/hip_fp16.h>

// APPNP encoder: e3 = ego + 0.9*A@(ego + 0.9*A@ego).
// R10: segment-tiled gathers. R9 showed occupancy 23->43% with zero time
// change: both SpMM passes are bound by ~4.8 TB/s of random 128B row fetches
// served by the Infinity Cache (12.8MB table >> 4MB per-XCD L2, no reuse).
// Fix: counting-sort key becomes (col_segment, row_local) with 7 segments of
// 16384 cols (2MB of fp16 table each). Both SpMMs loop segment-major with
// row accs in registers; co-resident blocks phase through segments together
// so each XCD's L2 holds the active 2MB slice -> ~32x reuse becomes L2 hits.
//  1. conv_init: fp32 ego -> fp16 table; init padded bucket cursors
//  2. bucket_scatter (512t): single-pass scatter into padded bucket slots
//  3. sort_spmm1 (512t): per-bucket (seg,row) counting sort -> rofs_g export,
//     then seg-major fused spmm1 (acc resident), writes e2 fp16
//  4. spmm2 (512t, per-bucket): seg-major pull SpMM from e2h -> fp32 out

#define USER_NUM 60000
#define ITEM_NUM 40000
#define N_NODES  100000
#define EMB      64
#define NNZ      3200000
#define OMA       0.9f   // 1 - alpha
#define BR       128     // rows per bucket
#define NB       782     // ceil(100000/128)
#define TILE     4096    // edges per scatter block
#define CAPB     4480    // padded slots per bucket (mean 4096, +6 sigma)
#define SEG_SHIFT 14     // 16384 cols/segment = 2MB of fp16 table
#define NSEG     7       // ceil(100000/16384)
#define NBIN     896     // NSEG * BR
#define RG       904     // rofs_g stride per bucket (NBIN+1 rounded to 8)

typedef float f32x4 __attribute__((ext_vector_type(4)));

// ---- 1) fp32 split ego -> flat fp16 table; init bucket cursors ----------
__global__ __launch_bounds__(256) void conv_init(const float* __restrict__ ue,
                                                 const float* __restrict__ ie,
                                                 __half* __restrict__ dst,
                                                 int* __restrict__ bcursor) {
    int t = blockIdx.x * 256 + threadIdx.x;       // 8 floats per thread
    if (t < NB) bcursor[t] = t * CAPB;
    const int total8 = N_NODES * EMB / 8;         // 800,000
    if (t >= total8) return;
    size_t f0 = (size_t)t * 8;
    const size_t usz = (size_t)USER_NUM * EMB;    // 3,840,000 (mult of 8)
    const float4* s4 = (f0 < usz) ? (const float4*)(ue + f0)
                                  : (const float4*)(ie + (f0 - usz));
    float4 x = s4[0], y = s4[1];
    union { float4 f4; __half2 h2[4]; } o;
    o.h2[0] = __floats2half2_rn(x.x, x.y);
    o.h2[1] = __floats2half2_rn(x.z, x.w);
    o.h2[2] = __floats2half2_rn(y.x, y.y);
    o.h2[3] = __floats2half2_rn(y.z, y.w);
    ((float4*)dst)[t] = o.f4;
}

// ---- 2) single-pass bucket scatter into padded slots (512 threads) ------
// entry = (col | row_local<<17, val*0.9)
__global__ __launch_bounds__(512) void bucket_scatter(const int* __restrict__ rows,
                                                      const int* __restrict__ cols,
                                                      const float* __restrict__ vals,
                                                      int* __restrict__ bcursor,
                                                      int2* __restrict__ ebuf) {
    __shared__ int bins[NB + 1];   // hist, then exclusive offsets
    __shared__ int lcur[NB];       // binning cursors, then global write offsets
    __shared__ int wsum[8];
    __shared__ int2 stage[TILE];
    int t = threadIdx.x;
    int lane = t & 63, w = t >> 6;           // 8 waves
    for (int b = t; b <= NB; b += 512) bins[b] = 0;
    __syncthreads();

    // load edges, histogram into bins (8 edges/thread)
    int e0 = blockIdx.x * TILE;
    int mybk[8], mypk[8];
    float myv[8];
#pragma unroll
    for (int j = 0; j < 8; ++j) {
        int i = e0 + t + 512 * j;
        mybk[j] = -1;
        if (i < NNZ) {
            int r = rows[i], c = cols[i];
            myv[j]  = vals[i] * OMA;
            mybk[j] = r >> 7;
            mypk[j] = c | ((r & 127) << 17);
            atomicAdd(&bins[mybk[j]], 1);
        }
    }
    __syncthreads();

    // register scan: 2 bins/thread, wave shfl scan + cross-wave combine
    int b0 = t * 2;
    int r0 = (b0     < NB) ? bins[b0]     : 0;
    int r1 = (b0 + 1 < NB) ? bins[b0 + 1] : 0;
    int s = r0 + r1;
    int incl = s;
#pragma unroll
    for (int off = 1; off < 64; off <<= 1) {
        int v = __shfl_up(incl, off, 64);
        if (lane >= off) incl += v;
    }
    if (lane == 63) wsum[w] = incl;
    __syncthreads();
    int prefix = 0;
#pragma unroll
    for (int i = 0; i < 8; ++i) if (i < w) prefix += wsum[i];
    int excl = prefix + incl - s;
    if (b0     < NB) { bins[b0]     = excl; lcur[b0]     = excl; excl += r0; }
    if (b0 + 1 < NB) { bins[b0 + 1] = excl; lcur[b0 + 1] = excl; }
    if (t == 511) bins[NB] = prefix + incl;   // total valid edges this tile
    __syncthreads();

    // bin into stage (bucket-sorted order)
#pragma unroll
    for (int j = 0; j < 8; ++j) {
        if (mybk[j] >= 0) {
            int p = atomicAdd(&lcur[mybk[j]], 1);
            stage[p] = make_int2(mypk[j], __float_as_int(myv[j]));
        }
    }
    __syncthreads();

    // Phase A: reserve global runs; lcur[b] := global_base - local_start
    for (int b = t; b < NB; b += 512) {
        int st = bins[b], en = bins[b + 1];
        int cnt = en - st;
        if (cnt > 0) lcur[b] = atomicAdd(&bcursor[b], cnt) - st;
    }
    __syncthreads();

    // Phase B: lane-parallel coalesced flush (binary search bucket of entry i)
    int total = bins[NB];
    for (int i = t; i < total; i += 512) {
        int lo = 0, hi = NB;
        while (hi - lo > 1) {
            int mid = (lo + hi) >> 1;
            if (bins[mid] <= i) lo = mid; else hi = mid;
        }
        ebuf[(size_t)(lcur[lo] + i)] = stage[i];
    }
}

// ---- 3) per-bucket (seg,row) sort + seg-major fused spmm1 (512t) --------
__global__ __launch_bounds__(512) void sort_spmm1(const int* __restrict__ bcursor,
                                                  int2* __restrict__ ebuf,
                                                  int* __restrict__ rofs_g,
                                                  const __half* __restrict__ ego_h,
                                                  const float* __restrict__ ue,
                                                  const float* __restrict__ ie,
                                                  __half* __restrict__ e2h) {
    __shared__ int2 stage[CAPB];
    __shared__ int rhist[NBIN], rofs[NBIN + 1], rcur[NBIN];
    __shared__ int wsum[8];
    int bk = blockIdx.x, t = threadIdx.x;
    int lane64 = t & 63, w = t >> 6;
    int s = bk * CAPB;
    int cnt = min(bcursor[bk] - s, CAPB);

    for (int i = t; i < NBIN; i += 512) rhist[i] = 0;
    __syncthreads();
    for (int i = t; i < cnt; i += 512) {
        int2 v = ebuf[(size_t)(s + i)];
        stage[i] = v;
        int bin = (((v.x & 0x1FFFF) >> SEG_SHIFT) << 7) | (v.x >> 17);
        atomicAdd(&rhist[bin], 1);
    }
    __syncthreads();
    // 512-thread scan over 896 bins (2/thread): wave shfl scan + combine
    int b0 = t * 2;
    int h0 = (b0     < NBIN) ? rhist[b0]     : 0;
    int h1 = (b0 + 1 < NBIN) ? rhist[b0 + 1] : 0;
    int sum = h0 + h1;
    int incl = sum;
#pragma unroll
    for (int off = 1; off < 64; off <<= 1) {
        int v = __shfl_up(incl, off, 64);
        if (lane64 >= off) incl += v;
    }
    if (lane64 == 63) wsum[w] = incl;
    __syncthreads();
    int prefix = 0;
#pragma unroll
    for (int i = 0; i < 8; ++i) if (i < w) prefix += wsum[i];
    int excl = prefix + incl - sum;
    if (b0     < NBIN) { rofs[b0]     = excl; rcur[b0]     = excl; excl += h0; }
    if (b0 + 1 < NBIN) { rofs[b0 + 1] = excl; rcur[b0 + 1] = excl; }
    if (t == 0) rofs[NBIN] = cnt;
    __syncthreads();

    // write row-sorted edges back (L2-local region); export rofs for spmm2
    for (int i = t; i < cnt; i += 512) {
        int2 v = stage[i];
        int bin = (((v.x & 0x1FFFF) >> SEG_SHIFT) << 7) | (v.x >> 17);
        int p = atomicAdd(&rcur[bin], 1);
        ebuf[(size_t)(s + p)] = v;
    }
    for (int i = t; i <= NBIN; i += 512) rofs_g[bk * RG + i] = rofs[i];
    __syncthreads();   // sorted edges + rofs visible block-wide

    // fused spmm1: 32 groups x 16 lanes; group owns 4 rows, accs resident,
    // segment-major so the active 2MB table slice stays L2-hot per XCD
    int lane  = t & 15;
    int qbase = (t & 63) & ~15;
    int rlb   = (t >> 4) << 2;              // 0..124
    const float2* srcv = (const float2*)ego_h;
    float4 acc[4];
#pragma unroll
    for (int rr = 0; rr < 4; ++rr) {
        int r = (bk << 7) + rlb + rr;
        acc[rr] = make_float4(0.f, 0.f, 0.f, 0.f);
        if (r < N_NODES) {
            const float* egop = (r < USER_NUM) ? (ue + (size_t)r * EMB)
                                               : (ie + (size_t)(r - USER_NUM) * EMB);
            acc[rr] = ((const float4*)egop)[lane];
        }
    }
    for (int seg = 0; seg < NSEG; ++seg) {
#pragma unroll
        for (int rr = 0; rr < 4; ++rr) {
            int bin = (seg << 7) | (rlb + rr);
            int ss = s + rofs[bin];
            int ee = s + rofs[bin + 1];
            for (int k = ss; k < ee; k += 16) {
                int rem = ee - k; if (rem > 16) rem = 16;
                int2 cv = (lane < rem) ? ebuf[(size_t)(k + lane)] : make_int2(0, 0);
                for (int j = 0; j < rem; ++j) {
                    int   cj = __shfl(cv.x, qbase + j, 64) & 0x1FFFF;
                    float vj = __int_as_float(__shfl(cv.y, qbase + j, 64));
                    union { float2 f2; __half2 h2[2]; } u;
                    u.f2 = srcv[(size_t)cj * 16 + lane];
                    float2 a = __half22float2(u.h2[0]);
                    float2 b = __half22float2(u.h2[1]);
                    acc[rr].x += vj * a.x; acc[rr].y += vj * a.y;
                    acc[rr].z += vj * b.x; acc[rr].w += vj * b.y;
                }
            }
        }
    }
#pragma unroll
    for (int rr = 0; rr < 4; ++rr) {
        int r = (bk << 7) + rlb + rr;
        if (r < N_NODES) {
            union { float2 f2; __half2 h2[2]; } o;
            o.h2[0] = __floats2half2_rn(acc[rr].x, acc[rr].y);
            o.h2[1] = __floats2half2_rn(acc[rr].z, acc[rr].w);
            ((float2*)e2h)[(size_t)r * 16 + lane] = o.f2;
        }
    }
}

// ---- 4) spmm2: per-bucket seg-major pull from e2h, fp32 nt out ----------
__global__ __launch_bounds__(512) void spmm2(const int* __restrict__ rofs_g,
                                             const int2* __restrict__ ebuf,
                                             const __half* __restrict__ src,
                                             const float* __restrict__ ue,
                                             const float* __restrict__ ie,
                                             float* __restrict__ outb) {
    __shared__ int rofs[NBIN + 1];
    int bk = blockIdx.x, t = threadIdx.x;
    for (int i = t; i <= NBIN; i += 512) rofs[i] = rofs_g[bk * RG + i];
    __syncthreads();
    int s = bk * CAPB;
    int lane  = t & 15;
    int qbase = (t & 63) & ~15;
    int rlb   = (t >> 4) << 2;
    const float2* srcv = (const float2*)src;
    const unsigned long long* eb8 = (const unsigned long long*)ebuf;
    float4 acc[4];
#pragma unroll
    for (int rr = 0; rr < 4; ++rr) {
        int r = (bk << 7) + rlb + rr;
        acc[rr] = make_float4(0.f, 0.f, 0.f, 0.f);
        if (r < N_NODES) {
            const float* egop = (r < USER_NUM) ? (ue + (size_t)r * EMB)
                                               : (ie + (size_t)(r - USER_NUM) * EMB);
            acc[rr] = ((const float4*)egop)[lane];
        }
    }
    for (int seg = 0; seg < NSEG; ++seg) {
#pragma unroll
        for (int rr = 0; rr < 4; ++rr) {
            int bin = (seg << 7) | (rlb + rr);
            int ss = s + rofs[bin];
            int ee = s + rofs[bin + 1];
            for (int k = ss; k < ee; k += 16) {
                int rem = ee - k; if (rem > 16) rem = 16;
                unsigned long long pv = 0;
                if (lane < rem) pv = __builtin_nontemporal_load(&eb8[(size_t)(k + lane)]);
                int cx = (int)(pv & 0xFFFFFFFFull);
                int cy = (int)(pv >> 32);
                for (int j = 0; j < rem; ++j) {
                    int   cj = __shfl(cx, qbase + j, 64) & 0x1FFFF;
                    float vj = __int_as_float(__shfl(cy, qbase + j, 64));
                    union { float2 f2; __half2 h2[2]; } u;
                    u.f2 = srcv[(size_t)cj * 16 + lane];
                    float2 a = __half22float2(u.h2[0]);
                    float2 b = __half22float2(u.h2[1]);
                    acc[rr].x += vj * a.x; acc[rr].y += vj * a.y;
                    acc[rr].z += vj * b.x; acc[rr].w += vj * b.y;
                }
            }
        }
    }
#pragma unroll
    for (int rr = 0; rr < 4; ++rr) {
        int r = (bk << 7) + rlb + rr;
        if (r < N_NODES) {
            f32x4 av = { acc[rr].x, acc[rr].y, acc[rr].z, acc[rr].w };
            __builtin_nontemporal_store(av, &((f32x4*)outb)[(size_t)r * 16 + lane]);
        }
    }
}

// ---- launch -------------------------------------------------------------
extern "C" void kernel_launch(void* const* d_in, const int* in_sizes, int n_in,
                              void* d_out, int out_size, void* d_ws, size_t ws_size,
                              hipStream_t stream) {
    const int*   rows = (const int*)d_in[0];
    const int*   cols = (const int*)d_in[1];
    const float* vals = (const float*)d_in[2];
    const float* ue   = (const float*)d_in[3];
    const float* ie   = (const float*)d_in[4];
    float* out = (float*)d_out;

    char* ws = (char*)d_ws;
    __half* ego_h    = (__half*)ws;                   // 12,800,000 B
    __half* e2h      = (__half*)(ws + 12800000);      // 12,800,000 B
    int2*   ebuf     = (int2*)(ws + 25600000);        // 782*4480*8 = 28,026,880 B
    int*    rofs_g   = (int*)(ws + 53626880);         // 782*904*4 = 2,827,712 B
    int*    bcursor  = (int*)(ws + 56454592);         // 3,128 B

    const int convBlocks = (N_NODES * EMB / 8 + 255) / 256;  // 3125
    conv_init<<<convBlocks, 256, 0, stream>>>(ue, ie, ego_h, bcursor);

    const int tiles = (NNZ + TILE - 1) / TILE;        // 782
    bucket_scatter<<<tiles, 512, 0, stream>>>(rows, cols, vals, bcursor, ebuf);
    sort_spmm1<<<NB, 512, 0, stream>>>(bcursor, ebuf, rofs_g, ego_h, ue, ie, e2h);
    spmm2<<<NB, 512, 0, stream>>>(rofs_g, ebuf, e2h, ue, ie, out);
}